// Round 5
// baseline (732.806 us; speedup 1.0000x reference)
//
#include <hip/hip_runtime.h>
#include <hip/hip_bf16.h>

#define B 2
#define H 32
#define S 2048
#define D 128
#define NT 32   // kv tiles of 64 per head

typedef __bf16 bf16x8 __attribute__((ext_vector_type(8)));
typedef float f32x4 __attribute__((ext_vector_type(4)));

union BF8U { unsigned int u[4]; unsigned short s[8]; bf16x8 b; int4 i4; };

static constexpr float INV_SQRT_D = 0.08838834764831845f; // 1/sqrt(128)
static constexpr float LOG2E = 1.4426950408889634f;
static constexpr int NROWS = B * H * S; // 131072

__device__ __forceinline__ unsigned short bfbits(float f) {
    union { __bf16 h; unsigned short s; } cv;
    cv.h = (__bf16)f;  // native cvt (RNE); exact for int codes
    return cv.s;
}
__device__ __forceinline__ unsigned int pack2bf(float a, float b) {
    union { unsigned short s[2]; unsigned int u; } cv;
    cv.s[0] = bfbits(a); cv.s[1] = bfbits(b);
    return cv.u;
}

// ---- quantize K -> fragment-major tiles [bh][t][slot 0..15][row 0..63]x16B
//      slot s = d/8; per-row scale * (1/sqrt(D)) * log2(e)
__global__ __launch_bounds__(256) void quant_k_kernel(
    const float* __restrict__ x, unsigned short* __restrict__ kpk,
    float* __restrict__ scl)
{
    const int row  = blockIdx.x * 4 + (threadIdx.x >> 6);
    const int lane = threadIdx.x & 63;
    const float2 v = *(const float2*)(x + (size_t)row * D + lane * 2);
    float m = fmaxf(fabsf(v.x), fabsf(v.y));
    #pragma unroll
    for (int off = 32; off; off >>= 1) m = fmaxf(m, __shfl_xor(m, off));
    const float scale = fmaxf(m / 127.0f, 1e-8f);
    const float q0 = fminf(fmaxf(rintf(v.x / scale), -127.0f), 127.0f);
    const float q1 = fminf(fmaxf(rintf(v.y / scale), -127.0f), 127.0f);
    const int bh = row >> 11, kv = row & 2047;
    const int t = kv >> 6, r = kv & 63, s = lane >> 2;
    unsigned short* dst = kpk + ((((size_t)bh * NT + t) * 16 + s) * 64 + r) * 8 + (lane & 3) * 2;
    *(unsigned int*)dst = pack2bf(q0, q1);
    if (lane == 0) scl[row] = scale * INV_SQRT_D * LOG2E;
}

// ---- quantize V -> fragment-major tiles [bh][t][slot 0..7][d 0..127]x16B
//      slot s=(kk,g): kk=s>>2, g=s&3 holds tokens {32kk+4g+0..3, 32kk+16+4g+0..3}
//      (16x16 PV A/B k-slot permutation baked in -> lane-local P, no exchange)
__global__ __launch_bounds__(256) void quant_v_kernel(
    const float* __restrict__ x, unsigned short* __restrict__ vpk,
    float* __restrict__ scl)
{
    __shared__ __align__(16) unsigned short vt[D][72];
    const int bh = blockIdx.y;
    const int t  = blockIdx.x;
    const int s0 = t * 64;
    const int tid = threadIdx.x;
    const int wave = tid >> 6, lane = tid & 63;

    #pragma unroll 1
    for (int i = 0; i < 16; i++) {
        const int tok = wave * 16 + i;
        const float2 v = *(const float2*)(x + ((size_t)bh * S + s0 + tok) * D + lane * 2);
        float m = fmaxf(fabsf(v.x), fabsf(v.y));
        #pragma unroll
        for (int off = 32; off; off >>= 1) m = fmaxf(m, __shfl_xor(m, off));
        const float scale = fmaxf(m / 127.0f, 1e-8f);
        const float q0 = fminf(fmaxf(rintf(v.x / scale), -127.0f), 127.0f);
        const float q1 = fminf(fmaxf(rintf(v.y / scale), -127.0f), 127.0f);
        vt[lane * 2    ][tok] = bfbits(q0);
        vt[lane * 2 + 1][tok] = bfbits(q1);
        if (lane == 0) scl[(size_t)bh * S + s0 + tok] = scale;
    }
    __syncthreads();
    const int d = tid & 127, sh = tid >> 7;
    const size_t tb = ((size_t)bh * NT + t) * 8192;
    #pragma unroll
    for (int p = 0; p < 4; p++) {
        const int s = p * 2 + sh, kk = s >> 2, gg = s & 3;
        BF8U o;
        *(unsigned long long*)&o.s[0] = *(const unsigned long long*)&vt[d][32 * kk + 4 * gg];
        *(unsigned long long*)&o.s[4] = *(const unsigned long long*)&vt[d][32 * kk + 16 + 4 * gg];
        *(int4*)(vpk + tb + ((size_t)s * 128 + d) * 8) = o.i4;
    }
}

// --------------------------- flash attention --------------------------------
// 16x16x32 swapped QK^T (small acc state -> 4 waves/SIMD), in-register softmax,
// zero-exchange PV, single-buffer LDS + reg-staged prefetch, XCD swizzle.
__global__ __launch_bounds__(256, 4) void attn_kernel(
    const float* __restrict__ Q, const unsigned short* __restrict__ Kpk,
    const float* __restrict__ Ksc, const unsigned short* __restrict__ Vpk,
    const float* __restrict__ Vsc, float* __restrict__ Out)
{
    __shared__ __align__(16) unsigned short Kb[8192];
    __shared__ __align__(16) unsigned short Vb[8192];
    __shared__ float KSb[64];
    __shared__ float VSb[64];

    const int wg = blockIdx.x;
    const int swz = (wg & 7) * 256 + (wg >> 3);   // 2048 % 8 == 0 -> bijective
    const int bh = swz >> 5;
    const int qt = swz & 31;
    const int tid = threadIdx.x;
    const int wave = tid >> 6, lane = tid & 63;
    const int g = lane >> 4, c = lane & 15;

    // Q fragments (B operand): lane (g,c): col q = c, k-slot d = kk*32+g*8+j
    bf16x8 qf[4];
    {
        const float* qp = Q + ((size_t)bh * S + qt * 64 + wave * 16 + c) * D + g * 8;
        #pragma unroll
        for (int kk = 0; kk < 4; kk++) {
            float4 a = *(const float4*)(qp + kk * 32);
            float4 b = *(const float4*)(qp + kk * 32 + 4);
            BF8U t8;
            t8.s[0] = bfbits(a.x); t8.s[1] = bfbits(a.y); t8.s[2] = bfbits(a.z); t8.s[3] = bfbits(a.w);
            t8.s[4] = bfbits(b.x); t8.s[5] = bfbits(b.y); t8.s[6] = bfbits(b.z); t8.s[7] = bfbits(b.w);
            qf[kk] = t8.b;
        }
    }

    f32x4 acc[8];
    const f32x4 zero = {0.f, 0.f, 0.f, 0.f};
    #pragma unroll
    for (int i = 0; i < 8; i++) acc[i] = zero;
    float mrun = -1e30f, lrun = 0.f;   // per-lane, q = c (dup over g after reduce)

    const size_t tile0 = (size_t)bh * NT * 8192;
    const size_t scb   = (size_t)bh * S;
    int4 kreg[4], vreg[4];
    float ksr = 0.f, vsr = 0.f;

    auto LOADN = [&](int tn) {
        const unsigned short* kp = Kpk + tile0 + (size_t)tn * 8192 + tid * 8;
        const unsigned short* vp = Vpk + tile0 + (size_t)tn * 8192 + tid * 8;
        #pragma unroll
        for (int p = 0; p < 4; p++) kreg[p] = *(const int4*)(kp + p * 2048);
        #pragma unroll
        for (int p = 0; p < 4; p++) vreg[p] = *(const int4*)(vp + p * 2048);
        if (wave == 0)      ksr = Ksc[scb + tn * 64 + lane];
        else if (wave == 1) vsr = Vsc[scb + tn * 64 + lane];
    };
    auto WRITEN = [&]() {
        #pragma unroll
        for (int p = 0; p < 4; p++) *(int4*)&Kb[(p * 256 + tid) * 8] = kreg[p];
        #pragma unroll
        for (int p = 0; p < 4; p++) *(int4*)&Vb[(p * 256 + tid) * 8] = vreg[p];
        if (wave == 0)      KSb[lane] = ksr;
        else if (wave == 1) VSb[lane] = vsr;
    };

    LOADN(0);

    #pragma unroll 1
    for (int t = 0; t < NT; t++) {
        __syncthreads();            // compute(t-1) done reading LDS; vmcnt drained
        WRITEN();
        __syncthreads();            // LDS tile t visible
        if (t + 1 < NT) LOADN(t + 1);  // overlap global latency with compute(t)

        // QK^T swapped: sacc[n] reg r at lane (g,c) = S[kv=16n+4g+r][q=c]
        f32x4 sacc[4];
        __builtin_amdgcn_s_setprio(1);
        #pragma unroll
        for (int n = 0; n < 4; n++) {
            sacc[n] = zero;
            #pragma unroll
            for (int kk = 0; kk < 4; kk++) {
                bf16x8 kf = *(const bf16x8*)&Kb[((4 * kk + g) * 64 + n * 16 + c) * 8];
                sacc[n] = __builtin_amdgcn_mfma_f32_16x16x32_bf16(kf, qf[kk], sacc[n], 0, 0, 0);
            }
        }
        __builtin_amdgcn_s_setprio(0);

        // scale (log2 domain) in place; row max over kv (lanes c,c+16,c+32,c+48)
        float mx = -1e30f;
        #pragma unroll
        for (int n = 0; n < 4; n++) {
            const f32x4 ks4 = *(const f32x4*)&KSb[n * 16 + 4 * g];
            #pragma unroll
            for (int j = 0; j < 4; j++) {
                sacc[n][j] *= ks4[j];
                mx = fmaxf(mx, sacc[n][j]);
            }
        }
        mx = fmaxf(mx, __shfl_xor(mx, 16));
        mx = fmaxf(mx, __shfl_xor(mx, 32));

        // defer-max (T13)
        if (!__all(mx - mrun <= 8.0f)) {
            const float mnew = fmaxf(mrun, mx);
            const float corr = exp2f(mrun - mnew);
            mrun = mnew;
            lrun *= corr;
            float cq[4];
            #pragma unroll
            for (int r = 0; r < 4; r++) cq[r] = __shfl(corr, 4 * g + r);
            #pragma unroll
            for (int nd = 0; nd < 8; nd++)
                #pragma unroll
                for (int r = 0; r < 4; r++) acc[nd][r] *= cq[r];
        }

        // P = 2^(S-m), fold v-scale, in place
        float ps = 0.f;
        #pragma unroll
        for (int n = 0; n < 4; n++) {
            const f32x4 vs4 = *(const f32x4*)&VSb[n * 16 + 4 * g];
            #pragma unroll
            for (int j = 0; j < 4; j++) {
                const float p = exp2f(sacc[n][j] - mrun);
                ps += p;
                sacc[n][j] = p * vs4[j];
            }
        }
        ps += __shfl_xor(ps, 16);
        ps += __shfl_xor(ps, 32);
        lrun += ps;

        // PV: pf[kk] slot j: j<4 -> pv[2kk][j], j>=4 -> pv[2kk+1][j-4] (lane-local)
        __builtin_amdgcn_s_setprio(1);
        #pragma unroll
        for (int kk = 0; kk < 2; kk++) {
            BF8U t8;
            t8.u[0] = pack2bf(sacc[2 * kk][0], sacc[2 * kk][1]);
            t8.u[1] = pack2bf(sacc[2 * kk][2], sacc[2 * kk][3]);
            t8.u[2] = pack2bf(sacc[2 * kk + 1][0], sacc[2 * kk + 1][1]);
            t8.u[3] = pack2bf(sacc[2 * kk + 1][2], sacc[2 * kk + 1][3]);
            const bf16x8 pf = t8.b;
            #pragma unroll
            for (int nd = 0; nd < 8; nd++) {
                bf16x8 vf = *(const bf16x8*)&Vb[((kk * 4 + g) * 128 + nd * 16 + c) * 8];
                acc[nd] = __builtin_amdgcn_mfma_f32_16x16x32_bf16(pf, vf, acc[nd], 0, 0, 0);
            }
        }
        __builtin_amdgcn_s_setprio(0);
    }

    // epilogue: gather per-row denom, store f32
    const float inv = 1.0f / lrun;
    float inv_q[4];
    #pragma unroll
    for (int r = 0; r < 4; r++) inv_q[r] = __shfl(inv, 4 * g + r);
    const size_t obase = ((size_t)bh * S + qt * 64 + wave * 16) * (size_t)D;
    #pragma unroll
    for (int r = 0; r < 4; r++) {
        const int q = 4 * g + r;
        #pragma unroll
        for (int nd = 0; nd < 8; nd++)
            Out[obase + (size_t)q * D + nd * 16 + c] = acc[nd][r] * inv_q[r];
    }
}

extern "C" void kernel_launch(void* const* d_in, const int* in_sizes, int n_in,
                              void* d_out, int out_size, void* d_ws, size_t ws_size,
                              hipStream_t stream) {
    const float* q = (const float*)d_in[0];
    const float* k = (const float*)d_in[1];
    const float* v = (const float*)d_in[2];
    float* out = (float*)d_out;

    const size_t ELEMS = (size_t)NROWS * D; // 16777216
    unsigned short* kpk = (unsigned short*)d_ws;
    unsigned short* vpk = kpk + ELEMS;
    float* ks = (float*)(vpk + ELEMS);
    float* vs = ks + NROWS;

    quant_k_kernel<<<NROWS / 4, 256, 0, stream>>>(k, kpk, ks);
    quant_v_kernel<<<dim3(NT, B * H), 256, 0, stream>>>(v, vpk, vs);
    attn_kernel<<<2048, 256, 0, stream>>>(q, kpk, ks, vpk, vs, out);
}

// Round 6
// 325.097 us; speedup vs baseline: 2.2541x; 2.2541x over previous
//
#include <hip/hip_runtime.h>
#include <hip/hip_bf16.h>

#define B 2
#define H 32
#define S 2048
#define D 128
#define NT 32   // kv tiles of 64 per head

typedef __bf16 bf16x8 __attribute__((ext_vector_type(8)));
typedef float f32x4 __attribute__((ext_vector_type(4)));

union BF8U { unsigned int u[4]; unsigned short s[8]; bf16x8 b; int4 i4; };

static constexpr float INV_SQRT_D = 0.08838834764831845f; // 1/sqrt(128)
static constexpr float LOG2E = 1.4426950408889634f;
static constexpr int NROWS = B * H * S; // 131072

__device__ __forceinline__ unsigned short bfbits(float f) {
    union { __bf16 h; unsigned short s; } cv;
    cv.h = (__bf16)f;  // native cvt (RNE); exact for int codes
    return cv.s;
}
__device__ __forceinline__ unsigned int pack2bf(float a, float b) {
    union { unsigned short s[2]; unsigned int u; } cv;
    cv.s[0] = bfbits(a); cv.s[1] = bfbits(b);
    return cv.u;
}

typedef unsigned int u32;
__device__ __forceinline__ void async_ld16(const unsigned short* g, unsigned short* l) {
    __builtin_amdgcn_global_load_lds(
        (const __attribute__((address_space(1))) u32*)g,
        (__attribute__((address_space(3))) u32*)l, 16, 0, 0);
}

// ---- quantize K -> fragment-major tiles [bh][t][slot 0..15][row 0..63]x16B
//      slot s = d/8; per-row scale * (1/sqrt(D)) * log2(e)
__global__ __launch_bounds__(256) void quant_k_kernel(
    const float* __restrict__ x, unsigned short* __restrict__ kpk,
    float* __restrict__ scl)
{
    const int row  = blockIdx.x * 4 + (threadIdx.x >> 6);
    const int lane = threadIdx.x & 63;
    const float2 v = *(const float2*)(x + (size_t)row * D + lane * 2);
    float m = fmaxf(fabsf(v.x), fabsf(v.y));
    #pragma unroll
    for (int off = 32; off; off >>= 1) m = fmaxf(m, __shfl_xor(m, off));
    const float scale = fmaxf(m / 127.0f, 1e-8f);
    const float q0 = fminf(fmaxf(rintf(v.x / scale), -127.0f), 127.0f);
    const float q1 = fminf(fmaxf(rintf(v.y / scale), -127.0f), 127.0f);
    const int bh = row >> 11, kv = row & 2047;
    const int t = kv >> 6, r = kv & 63, s = lane >> 2;
    unsigned short* dst = kpk + ((((size_t)bh * NT + t) * 16 + s) * 64 + r) * 8 + (lane & 3) * 2;
    *(unsigned int*)dst = pack2bf(q0, q1);
    if (lane == 0) scl[row] = scale * INV_SQRT_D * LOG2E;
}

// ---- quantize V -> fragment-major tiles [bh][t][slot 0..7][d 0..127]x16B
//      slot s=(kk,g): kk=s>>2, g=s&3 holds tokens {32kk+4g+0..3, 32kk+16+4g+0..3}
__global__ __launch_bounds__(256) void quant_v_kernel(
    const float* __restrict__ x, unsigned short* __restrict__ vpk,
    float* __restrict__ scl)
{
    __shared__ __align__(16) unsigned short vt[D][72];
    const int bh = blockIdx.y;
    const int t  = blockIdx.x;
    const int s0 = t * 64;
    const int tid = threadIdx.x;
    const int wave = tid >> 6, lane = tid & 63;

    #pragma unroll 1
    for (int i = 0; i < 16; i++) {
        const int tok = wave * 16 + i;
        const float2 v = *(const float2*)(x + ((size_t)bh * S + s0 + tok) * D + lane * 2);
        float m = fmaxf(fabsf(v.x), fabsf(v.y));
        #pragma unroll
        for (int off = 32; off; off >>= 1) m = fmaxf(m, __shfl_xor(m, off));
        const float scale = fmaxf(m / 127.0f, 1e-8f);
        const float q0 = fminf(fmaxf(rintf(v.x / scale), -127.0f), 127.0f);
        const float q1 = fminf(fmaxf(rintf(v.y / scale), -127.0f), 127.0f);
        vt[lane * 2    ][tok] = bfbits(q0);
        vt[lane * 2 + 1][tok] = bfbits(q1);
        if (lane == 0) scl[(size_t)bh * S + s0 + tok] = scale;
    }
    __syncthreads();
    const int d = tid & 127, sh = tid >> 7;
    const size_t tb = ((size_t)bh * NT + t) * 8192;
    #pragma unroll
    for (int p = 0; p < 4; p++) {
        const int s = p * 2 + sh, kk = s >> 2, gg = s & 3;
        BF8U o;
        *(unsigned long long*)&o.s[0] = *(const unsigned long long*)&vt[d][32 * kk + 4 * gg];
        *(unsigned long long*)&o.s[4] = *(const unsigned long long*)&vt[d][32 * kk + 16 + 4 * gg];
        *(int4*)(vpk + tb + ((size_t)s * 128 + d) * 8) = o.i4;
    }
}

// --------------------------- flash attention --------------------------------
// 16x16x32 swapped QK^T, 32 q/wave (two q-columns share every LDS fragment
// read), global_load_lds staging (no staging VGPRs, no ds_writes),
// in-register softmax, zero-exchange PV, XCD-swizzled grid.
__global__ __launch_bounds__(256, 3) void attn_kernel(
    const float* __restrict__ Q, const unsigned short* __restrict__ Kpk,
    const float* __restrict__ Ksc, const unsigned short* __restrict__ Vpk,
    const float* __restrict__ Vsc, float* __restrict__ Out)
{
    __shared__ __align__(16) unsigned short Kb[8192];
    __shared__ __align__(16) unsigned short Vb[8192];

    const int wg = blockIdx.x;
    const int swz = (wg & 7) * 128 + (wg >> 3);   // 1024 % 8 == 0 -> bijective
    const int bh = swz >> 4;
    const int qt = swz & 15;
    const int tid = threadIdx.x;
    const int wave = tid >> 6, lane = tid & 63;
    const int g = lane >> 4, c = lane & 15;

    // Q fragments for two q-columns (B operand): col q = c (+16), k = kk*32+g*8+j
    bf16x8 qfA[4], qfB[4];
    {
        const float* qpA = Q + ((size_t)bh * S + qt * 128 + wave * 32 + c) * D + g * 8;
        const float* qpB = qpA + 16 * D;
        #pragma unroll
        for (int kk = 0; kk < 4; kk++) {
            float4 a = *(const float4*)(qpA + kk * 32);
            float4 b = *(const float4*)(qpA + kk * 32 + 4);
            BF8U t8;
            t8.s[0] = bfbits(a.x); t8.s[1] = bfbits(a.y); t8.s[2] = bfbits(a.z); t8.s[3] = bfbits(a.w);
            t8.s[4] = bfbits(b.x); t8.s[5] = bfbits(b.y); t8.s[6] = bfbits(b.z); t8.s[7] = bfbits(b.w);
            qfA[kk] = t8.b;
            a = *(const float4*)(qpB + kk * 32);
            b = *(const float4*)(qpB + kk * 32 + 4);
            t8.s[0] = bfbits(a.x); t8.s[1] = bfbits(a.y); t8.s[2] = bfbits(a.z); t8.s[3] = bfbits(a.w);
            t8.s[4] = bfbits(b.x); t8.s[5] = bfbits(b.y); t8.s[6] = bfbits(b.z); t8.s[7] = bfbits(b.w);
            qfB[kk] = t8.b;
        }
    }

    f32x4 accA[8], accB[8];
    const f32x4 zero = {0.f, 0.f, 0.f, 0.f};
    #pragma unroll
    for (int i = 0; i < 8; i++) { accA[i] = zero; accB[i] = zero; }
    float mA = -1e30f, lA = 0.f, mB = -1e30f, lB = 0.f;

    const size_t tbase = (size_t)bh * NT * 8192;
    const size_t scb   = (size_t)bh * S;

    #pragma unroll 1
    for (int t = 0; t < NT; t++) {
        if (t) __syncthreads();           // all waves done reading tile t-1
        {
            const unsigned short* kt = Kpk + tbase + (size_t)t * 8192;
            const unsigned short* vt = Vpk + tbase + (size_t)t * 8192;
            #pragma unroll
            for (int i = 0; i < 4; i++) {
                const int ch = wave * 4 + i;           // 16 x 1KB chunks each
                async_ld16(kt + ch * 512 + lane * 8, &Kb[ch * 512]);
                async_ld16(vt + ch * 512 + lane * 8, &Vb[ch * 512]);
            }
        }
        __syncthreads();                  // barrier drains vmcnt -> tile ready

        // QK^T swapped: s[n] reg r at lane (g,c) = S[kv=16n+4g+r][q=c(,+16)]
        f32x4 sA[4], sB[4];
        __builtin_amdgcn_s_setprio(1);
        #pragma unroll
        for (int n = 0; n < 4; n++) {
            sA[n] = zero; sB[n] = zero;
            #pragma unroll
            for (int kk = 0; kk < 4; kk++) {
                bf16x8 kf = *(const bf16x8*)&Kb[((4 * kk + g) * 64 + n * 16 + c) * 8];
                sA[n] = __builtin_amdgcn_mfma_f32_16x16x32_bf16(kf, qfA[kk], sA[n], 0, 0, 0);
                sB[n] = __builtin_amdgcn_mfma_f32_16x16x32_bf16(kf, qfB[kk], sB[n], 0, 0, 0);
            }
        }
        __builtin_amdgcn_s_setprio(0);

        // K scales (log2 domain) direct from global (L1-resident); row max
        const float* kscp = Ksc + scb + t * 64;
        float mxA = -1e30f, mxB = -1e30f;
        #pragma unroll
        for (int n = 0; n < 4; n++) {
            const f32x4 ks4 = *(const f32x4*)(kscp + n * 16 + 4 * g);
            #pragma unroll
            for (int j = 0; j < 4; j++) {
                sA[n][j] *= ks4[j];
                sB[n][j] *= ks4[j];
                mxA = fmaxf(mxA, sA[n][j]);
                mxB = fmaxf(mxB, sB[n][j]);
            }
        }
        mxA = fmaxf(mxA, __shfl_xor(mxA, 16));
        mxA = fmaxf(mxA, __shfl_xor(mxA, 32));
        mxB = fmaxf(mxB, __shfl_xor(mxB, 16));
        mxB = fmaxf(mxB, __shfl_xor(mxB, 32));

        // defer-max (T13) per q-column
        if (!__all(mxA - mA <= 8.0f)) {
            const float mnew = fmaxf(mA, mxA);
            const float corr = exp2f(mA - mnew);
            mA = mnew; lA *= corr;
            float cq[4];
            #pragma unroll
            for (int r = 0; r < 4; r++) cq[r] = __shfl(corr, 4 * g + r);
            #pragma unroll
            for (int nd = 0; nd < 8; nd++)
                #pragma unroll
                for (int r = 0; r < 4; r++) accA[nd][r] *= cq[r];
        }
        if (!__all(mxB - mB <= 8.0f)) {
            const float mnew = fmaxf(mB, mxB);
            const float corr = exp2f(mB - mnew);
            mB = mnew; lB *= corr;
            float cq[4];
            #pragma unroll
            for (int r = 0; r < 4; r++) cq[r] = __shfl(corr, 4 * g + r);
            #pragma unroll
            for (int nd = 0; nd < 8; nd++)
                #pragma unroll
                for (int r = 0; r < 4; r++) accB[nd][r] *= cq[r];
        }

        // P = 2^(S-m), fold v-scale, in place
        const float* vscp = Vsc + scb + t * 64;
        float psA = 0.f, psB = 0.f;
        #pragma unroll
        for (int n = 0; n < 4; n++) {
            const f32x4 vs4 = *(const f32x4*)(vscp + n * 16 + 4 * g);
            #pragma unroll
            for (int j = 0; j < 4; j++) {
                float p = exp2f(sA[n][j] - mA);
                psA += p;
                sA[n][j] = p * vs4[j];
                p = exp2f(sB[n][j] - mB);
                psB += p;
                sB[n][j] = p * vs4[j];
            }
        }
        psA += __shfl_xor(psA, 16);
        psA += __shfl_xor(psA, 32);
        lA += psA;
        psB += __shfl_xor(psB, 16);
        psB += __shfl_xor(psB, 32);
        lB += psB;

        // PV: pf slot j: j<4 -> s[2kk][j], j>=4 -> s[2kk+1][j-4] (lane-local);
        // V packed slot order matches -> zero exchange. vf shared by A and B.
        __builtin_amdgcn_s_setprio(1);
        #pragma unroll
        for (int kk = 0; kk < 2; kk++) {
            BF8U a8, b8;
            a8.u[0] = pack2bf(sA[2 * kk][0], sA[2 * kk][1]);
            a8.u[1] = pack2bf(sA[2 * kk][2], sA[2 * kk][3]);
            a8.u[2] = pack2bf(sA[2 * kk + 1][0], sA[2 * kk + 1][1]);
            a8.u[3] = pack2bf(sA[2 * kk + 1][2], sA[2 * kk + 1][3]);
            b8.u[0] = pack2bf(sB[2 * kk][0], sB[2 * kk][1]);
            b8.u[1] = pack2bf(sB[2 * kk][2], sB[2 * kk][3]);
            b8.u[2] = pack2bf(sB[2 * kk + 1][0], sB[2 * kk + 1][1]);
            b8.u[3] = pack2bf(sB[2 * kk + 1][2], sB[2 * kk + 1][3]);
            const bf16x8 pfA = a8.b, pfB = b8.b;
            #pragma unroll
            for (int nd = 0; nd < 8; nd++) {
                bf16x8 vf = *(const bf16x8*)&Vb[((kk * 4 + g) * 128 + nd * 16 + c) * 8];
                accA[nd] = __builtin_amdgcn_mfma_f32_16x16x32_bf16(pfA, vf, accA[nd], 0, 0, 0);
                accB[nd] = __builtin_amdgcn_mfma_f32_16x16x32_bf16(pfB, vf, accB[nd], 0, 0, 0);
            }
        }
        __builtin_amdgcn_s_setprio(0);
    }

    // epilogue: per-row denom gather, store f32
    const float invA = 1.0f / lA, invB = 1.0f / lB;
    float iqA[4], iqB[4];
    #pragma unroll
    for (int r = 0; r < 4; r++) {
        iqA[r] = __shfl(invA, 4 * g + r);
        iqB[r] = __shfl(invB, 4 * g + r);
    }
    const size_t obase = ((size_t)bh * S + qt * 128 + wave * 32) * (size_t)D;
    #pragma unroll
    for (int r = 0; r < 4; r++) {
        const int q = 4 * g + r;
        #pragma unroll
        for (int nd = 0; nd < 8; nd++) {
            Out[obase + (size_t)q * D + nd * 16 + c] = accA[nd][r] * iqA[r];
            Out[obase + (size_t)(q + 16) * D + nd * 16 + c] = accB[nd][r] * iqB[r];
        }
    }
}

extern "C" void kernel_launch(void* const* d_in, const int* in_sizes, int n_in,
                              void* d_out, int out_size, void* d_ws, size_t ws_size,
                              hipStream_t stream) {
    const float* q = (const float*)d_in[0];
    const float* k = (const float*)d_in[1];
    const float* v = (const float*)d_in[2];
    float* out = (float*)d_out;

    const size_t ELEMS = (size_t)NROWS * D; // 16777216
    unsigned short* kpk = (unsigned short*)d_ws;
    unsigned short* vpk = kpk + ELEMS;
    float* ks = (float*)(vpk + ELEMS);
    float* vs = ks + NROWS;

    quant_k_kernel<<<NROWS / 4, 256, 0, stream>>>(k, kpk, ks);
    quant_v_kernel<<<dim3(NT, B * H), 256, 0, stream>>>(v, vpk, vs);
    attn_kernel<<<1024, 256, 0, stream>>>(q, kpk, ks, vpk, vs, out);
}

// Round 7
// 284.986 us; speedup vs baseline: 2.5714x; 1.1407x over previous
//
#include <hip/hip_runtime.h>
#include <hip/hip_bf16.h>

#define B 2
#define H 32
#define S 2048
#define D 128
#define NT 32   // kv tiles of 64 per head

typedef __bf16 bf16x8 __attribute__((ext_vector_type(8)));
typedef float f32x4 __attribute__((ext_vector_type(4)));

union BF8U { unsigned int u[4]; unsigned short s[8]; bf16x8 b; int4 i4; };

static constexpr float INV_SQRT_D = 0.08838834764831845f; // 1/sqrt(128)
static constexpr float LOG2E = 1.4426950408889634f;
static constexpr int NROWS = B * H * S; // 131072

__device__ __forceinline__ unsigned short bfbits(float f) {
    union { __bf16 h; unsigned short s; } cv;
    cv.h = (__bf16)f;  // native cvt (RNE); exact for int codes
    return cv.s;
}
__device__ __forceinline__ unsigned int pack2bf(float a, float b) {
    union { unsigned short s[2]; unsigned int u; } cv;
    cv.s[0] = bfbits(a); cv.s[1] = bfbits(b);
    return cv.u;
}

typedef unsigned int u32;
__device__ __forceinline__ void async_ld16(const unsigned short* g, unsigned short* l) {
    __builtin_amdgcn_global_load_lds(
        (const __attribute__((address_space(1))) u32*)g,
        (__attribute__((address_space(3))) u32*)l, 16, 0, 0);
}

// ---- quantize K -> fragment-major tiles [bh][t][slot 0..15][row 0..63]x16B
//      slot s = d/8; per-row scale * (1/sqrt(D)) * log2(e)
__global__ __launch_bounds__(256) void quant_k_kernel(
    const float* __restrict__ x, unsigned short* __restrict__ kpk,
    float* __restrict__ scl)
{
    const int row  = blockIdx.x * 4 + (threadIdx.x >> 6);
    const int lane = threadIdx.x & 63;
    const float2 v = *(const float2*)(x + (size_t)row * D + lane * 2);
    float m = fmaxf(fabsf(v.x), fabsf(v.y));
    #pragma unroll
    for (int off = 32; off; off >>= 1) m = fmaxf(m, __shfl_xor(m, off));
    const float scale = fmaxf(m / 127.0f, 1e-8f);
    const float q0 = fminf(fmaxf(rintf(v.x / scale), -127.0f), 127.0f);
    const float q1 = fminf(fmaxf(rintf(v.y / scale), -127.0f), 127.0f);
    const int bh = row >> 11, kv = row & 2047;
    const int t = kv >> 6, r = kv & 63, s = lane >> 2;
    unsigned short* dst = kpk + ((((size_t)bh * NT + t) * 16 + s) * 64 + r) * 8 + (lane & 3) * 2;
    *(unsigned int*)dst = pack2bf(q0, q1);
    if (lane == 0) scl[row] = scale * INV_SQRT_D * LOG2E;
}

// ---- quantize V -> fragment-major tiles [bh][t][slot 0..7][d 0..127]x16B
//      slot s=(kk,g): kk=s>>2, g=s&3 holds tokens {32kk+4g+0..3, 32kk+16+4g+0..3}
__global__ __launch_bounds__(256) void quant_v_kernel(
    const float* __restrict__ x, unsigned short* __restrict__ vpk,
    float* __restrict__ scl)
{
    __shared__ __align__(16) unsigned short vt[D][72];
    const int bh = blockIdx.y;
    const int t  = blockIdx.x;
    const int s0 = t * 64;
    const int tid = threadIdx.x;
    const int wave = tid >> 6, lane = tid & 63;

    #pragma unroll 1
    for (int i = 0; i < 16; i++) {
        const int tok = wave * 16 + i;
        const float2 v = *(const float2*)(x + ((size_t)bh * S + s0 + tok) * D + lane * 2);
        float m = fmaxf(fabsf(v.x), fabsf(v.y));
        #pragma unroll
        for (int off = 32; off; off >>= 1) m = fmaxf(m, __shfl_xor(m, off));
        const float scale = fmaxf(m / 127.0f, 1e-8f);
        const float q0 = fminf(fmaxf(rintf(v.x / scale), -127.0f), 127.0f);
        const float q1 = fminf(fmaxf(rintf(v.y / scale), -127.0f), 127.0f);
        vt[lane * 2    ][tok] = bfbits(q0);
        vt[lane * 2 + 1][tok] = bfbits(q1);
        if (lane == 0) scl[(size_t)bh * S + s0 + tok] = scale;
    }
    __syncthreads();
    const int d = tid & 127, sh = tid >> 7;
    const size_t tb = ((size_t)bh * NT + t) * 8192;
    #pragma unroll
    for (int p = 0; p < 4; p++) {
        const int s = p * 2 + sh, kk = s >> 2, gg = s & 3;
        BF8U o;
        *(unsigned long long*)&o.s[0] = *(const unsigned long long*)&vt[d][32 * kk + 4 * gg];
        *(unsigned long long*)&o.s[4] = *(const unsigned long long*)&vt[d][32 * kk + 16 + 4 * gg];
        *(int4*)(vpk + tb + ((size_t)s * 128 + d) * 8) = o.i4;
    }
}

// --------------------------- flash attention --------------------------------
// 16x16x32 swapped QK^T, 32 q/wave, global_load_lds DOUBLE-BUFFERED 2-phase
// pipeline (stage t+1 during compute t; one barrier/tile drains vmcnt),
// in-register softmax, zero-exchange PV, XCD-swizzled grid.
__global__ __launch_bounds__(256, 2) void attn_kernel(
    const float* __restrict__ Q, const unsigned short* __restrict__ Kpk,
    const float* __restrict__ Ksc, const unsigned short* __restrict__ Vpk,
    const float* __restrict__ Vsc, float* __restrict__ Out)
{
    __shared__ __align__(16) unsigned short Kb[2][8192];
    __shared__ __align__(16) unsigned short Vb[2][8192];

    const int wg = blockIdx.x;
    const int swz = (wg & 7) * 128 + (wg >> 3);   // 1024 % 8 == 0 -> bijective
    const int bh = swz >> 4;
    const int qt = swz & 15;
    const int tid = threadIdx.x;
    const int wave = tid >> 6, lane = tid & 63;
    const int g = lane >> 4, c = lane & 15;

    const size_t tbase = (size_t)bh * NT * 8192;
    const size_t scb   = (size_t)bh * S;

    // stage tile tn into LDS buffer pb (async; completion via barrier's vmcnt)
    auto STAGE = [&](int tn, int pb) {
        const unsigned short* kt = Kpk + tbase + (size_t)tn * 8192;
        const unsigned short* vt = Vpk + tbase + (size_t)tn * 8192;
        #pragma unroll
        for (int i = 0; i < 4; i++) {
            const int ch = wave * 4 + i;           // 16 x 1KB chunks each
            async_ld16(kt + ch * 512 + lane * 8, &Kb[pb][ch * 512]);
            async_ld16(vt + ch * 512 + lane * 8, &Vb[pb][ch * 512]);
        }
    };

    // Q fragments for two q-columns (B operand): col q = c (+16), k = kk*32+g*8+j
    bf16x8 qfA[4], qfB[4];
    {
        const float* qpA = Q + ((size_t)bh * S + qt * 128 + wave * 32 + c) * D + g * 8;
        const float* qpB = qpA + 16 * D;
        #pragma unroll
        for (int kk = 0; kk < 4; kk++) {
            float4 a = *(const float4*)(qpA + kk * 32);
            float4 b = *(const float4*)(qpA + kk * 32 + 4);
            BF8U t8;
            t8.s[0] = bfbits(a.x); t8.s[1] = bfbits(a.y); t8.s[2] = bfbits(a.z); t8.s[3] = bfbits(a.w);
            t8.s[4] = bfbits(b.x); t8.s[5] = bfbits(b.y); t8.s[6] = bfbits(b.z); t8.s[7] = bfbits(b.w);
            qfA[kk] = t8.b;
            a = *(const float4*)(qpB + kk * 32);
            b = *(const float4*)(qpB + kk * 32 + 4);
            t8.s[0] = bfbits(a.x); t8.s[1] = bfbits(a.y); t8.s[2] = bfbits(a.z); t8.s[3] = bfbits(a.w);
            t8.s[4] = bfbits(b.x); t8.s[5] = bfbits(b.y); t8.s[6] = bfbits(b.z); t8.s[7] = bfbits(b.w);
            qfB[kk] = t8.b;
        }
    }

    f32x4 accA[8], accB[8];
    const f32x4 zero = {0.f, 0.f, 0.f, 0.f};
    #pragma unroll
    for (int i = 0; i < 8; i++) { accA[i] = zero; accB[i] = zero; }
    float mA = -1e30f, lA = 0.f, mB = -1e30f, lB = 0.f;

    STAGE(0, 0);
    __syncthreads();                      // drains vmcnt -> buf0 ready

    #pragma unroll 1
    for (int t = 0; t < NT; t++) {
        const int cur = t & 1;
        if (t + 1 < NT) STAGE(t + 1, cur ^ 1);   // in flight during compute(t)

        // QK^T swapped: s[n] reg r at lane (g,c) = S[kv=16n+4g+r][q=c(,+16)]
        f32x4 sA[4], sB[4];
        __builtin_amdgcn_s_setprio(1);
        #pragma unroll
        for (int n = 0; n < 4; n++) {
            sA[n] = zero; sB[n] = zero;
            #pragma unroll
            for (int kk = 0; kk < 4; kk++) {
                bf16x8 kf = *(const bf16x8*)&Kb[cur][((4 * kk + g) * 64 + n * 16 + c) * 8];
                sA[n] = __builtin_amdgcn_mfma_f32_16x16x32_bf16(kf, qfA[kk], sA[n], 0, 0, 0);
                sB[n] = __builtin_amdgcn_mfma_f32_16x16x32_bf16(kf, qfB[kk], sB[n], 0, 0, 0);
            }
        }
        __builtin_amdgcn_s_setprio(0);

        // K scales (log2 domain) direct from global (L1/L2-resident); row max
        const float* kscp = Ksc + scb + t * 64;
        float mxA = -1e30f, mxB = -1e30f;
        #pragma unroll
        for (int n = 0; n < 4; n++) {
            const f32x4 ks4 = *(const f32x4*)(kscp + n * 16 + 4 * g);
            #pragma unroll
            for (int j = 0; j < 4; j++) {
                sA[n][j] *= ks4[j];
                sB[n][j] *= ks4[j];
                mxA = fmaxf(mxA, sA[n][j]);
                mxB = fmaxf(mxB, sB[n][j]);
            }
        }
        mxA = fmaxf(mxA, __shfl_xor(mxA, 16));
        mxA = fmaxf(mxA, __shfl_xor(mxA, 32));
        mxB = fmaxf(mxB, __shfl_xor(mxB, 16));
        mxB = fmaxf(mxB, __shfl_xor(mxB, 32));

        // defer-max (T13) per q-column
        if (!__all(mxA - mA <= 8.0f)) {
            const float mnew = fmaxf(mA, mxA);
            const float corr = exp2f(mA - mnew);
            mA = mnew; lA *= corr;
            float cq[4];
            #pragma unroll
            for (int r = 0; r < 4; r++) cq[r] = __shfl(corr, 4 * g + r);
            #pragma unroll
            for (int nd = 0; nd < 8; nd++)
                #pragma unroll
                for (int r = 0; r < 4; r++) accA[nd][r] *= cq[r];
        }
        if (!__all(mxB - mB <= 8.0f)) {
            const float mnew = fmaxf(mB, mxB);
            const float corr = exp2f(mB - mnew);
            mB = mnew; lB *= corr;
            float cq[4];
            #pragma unroll
            for (int r = 0; r < 4; r++) cq[r] = __shfl(corr, 4 * g + r);
            #pragma unroll
            for (int nd = 0; nd < 8; nd++)
                #pragma unroll
                for (int r = 0; r < 4; r++) accB[nd][r] *= cq[r];
        }

        // P = 2^(S-m), fold v-scale, in place
        const float* vscp = Vsc + scb + t * 64;
        float psA = 0.f, psB = 0.f;
        #pragma unroll
        for (int n = 0; n < 4; n++) {
            const f32x4 vs4 = *(const f32x4*)(vscp + n * 16 + 4 * g);
            #pragma unroll
            for (int j = 0; j < 4; j++) {
                float p = exp2f(sA[n][j] - mA);
                psA += p;
                sA[n][j] = p * vs4[j];
                p = exp2f(sB[n][j] - mB);
                psB += p;
                sB[n][j] = p * vs4[j];
            }
        }
        psA += __shfl_xor(psA, 16);
        psA += __shfl_xor(psA, 32);
        lA += psA;
        psB += __shfl_xor(psB, 16);
        psB += __shfl_xor(psB, 32);
        lB += psB;

        // PV: pf slot j: j<4 -> s[2kk][j], j>=4 -> s[2kk+1][j-4] (lane-local);
        // V packed slot order matches -> zero exchange. vf shared by A and B.
        __builtin_amdgcn_s_setprio(1);
        #pragma unroll
        for (int kk = 0; kk < 2; kk++) {
            BF8U a8, b8;
            a8.u[0] = pack2bf(sA[2 * kk][0], sA[2 * kk][1]);
            a8.u[1] = pack2bf(sA[2 * kk][2], sA[2 * kk][3]);
            a8.u[2] = pack2bf(sA[2 * kk + 1][0], sA[2 * kk + 1][1]);
            a8.u[3] = pack2bf(sA[2 * kk + 1][2], sA[2 * kk + 1][3]);
            b8.u[0] = pack2bf(sB[2 * kk][0], sB[2 * kk][1]);
            b8.u[1] = pack2bf(sB[2 * kk][2], sB[2 * kk][3]);
            b8.u[2] = pack2bf(sB[2 * kk + 1][0], sB[2 * kk + 1][1]);
            b8.u[3] = pack2bf(sB[2 * kk + 1][2], sB[2 * kk + 1][3]);
            const bf16x8 pfA = a8.b, pfB = b8.b;
            #pragma unroll
            for (int nd = 0; nd < 8; nd++) {
                bf16x8 vf = *(const bf16x8*)&Vb[cur][((kk * 4 + g) * 128 + nd * 16 + c) * 8];
                accA[nd] = __builtin_amdgcn_mfma_f32_16x16x32_bf16(pfA, vf, accA[nd], 0, 0, 0);
                accB[nd] = __builtin_amdgcn_mfma_f32_16x16x32_bf16(pfB, vf, accB[nd], 0, 0, 0);
            }
        }
        __builtin_amdgcn_s_setprio(0);

        __syncthreads();   // drains vmcnt (stage t+1 landed) + LDS reuse barrier
    }

    // epilogue: per-row denom gather, store f32
    const float invA = 1.0f / lA, invB = 1.0f / lB;
    float iqA[4], iqB[4];
    #pragma unroll
    for (int r = 0; r < 4; r++) {
        iqA[r] = __shfl(invA, 4 * g + r);
        iqB[r] = __shfl(invB, 4 * g + r);
    }
    const size_t obase = ((size_t)bh * S + qt * 128 + wave * 32) * (size_t)D;
    #pragma unroll
    for (int r = 0; r < 4; r++) {
        const int q = 4 * g + r;
        #pragma unroll
        for (int nd = 0; nd < 8; nd++) {
            Out[obase + (size_t)q * D + nd * 16 + c] = accA[nd][r] * iqA[r];
            Out[obase + (size_t)(q + 16) * D + nd * 16 + c] = accB[nd][r] * iqB[r];
        }
    }
}

extern "C" void kernel_launch(void* const* d_in, const int* in_sizes, int n_in,
                              void* d_out, int out_size, void* d_ws, size_t ws_size,
                              hipStream_t stream) {
    const float* q = (const float*)d_in[0];
    const float* k = (const float*)d_in[1];
    const float* v = (const float*)d_in[2];
    float* out = (float*)d_out;

    const size_t ELEMS = (size_t)NROWS * D; // 16777216
    unsigned short* kpk = (unsigned short*)d_ws;
    unsigned short* vpk = kpk + ELEMS;
    float* ks = (float*)(vpk + ELEMS);
    float* vs = ks + NROWS;

    quant_k_kernel<<<NROWS / 4, 256, 0, stream>>>(k, kpk, ks);
    quant_v_kernel<<<dim3(NT, B * H), 256, 0, stream>>>(v, vpk, vs);
    attn_kernel<<<1024, 256, 0, stream>>>(q, kpk, ks, vpk, vs, out);
}